// Round 13
// baseline (80.603 us; speedup 1.0000x reference)
//
#include <hip/hip_runtime.h>
#include <math.h>

// Tiny 2-token transformer, E=30, H=3, D=10, B=1e6 — transposed-MFMA version.
// Y^T = W·X^T per layer with mfma_f32_16x16x32_f16; A = prep-packed weights
// (bias folded at k=30), B = activations^T built from C-regs by register
// packing (κ(g,e) = e<4 ? 4g+e : 16+4g+(e-4) shared by A and B).
// Round 13: GELU back to deg-9 (round 12's deg-6 cut poly accuracy to ~1e-3
// and failed absmax at 0.047 — degree costs no VGPRs, coeffs are SGPR-uniform).
// KEEP from round 12: __launch_bounds__(256,4) occupancy push + exp->exp2 fold
// (q pre-scaled by log2(e)/sqrt(10) in prep; native v_exp_f32 is 2^x).

typedef _Float16 h8 __attribute__((ext_vector_type(8)));
typedef _Float16 h2v __attribute__((ext_vector_type(2)));
typedef float f4 __attribute__((ext_vector_type(4)));
typedef f4 f4u __attribute__((aligned(4)));

#define EPS 1e-5f
#define GDEG 9

struct GeluCU { unsigned c[GDEG + 2]; };   // duplicated-half f16 pairs

__device__ __forceinline__ f4 MF(h8 a, h8 b, f4 c) {
    return __builtin_amdgcn_mfma_f32_16x16x32_f16(a, b, c, 0, 0, 0);
}

struct GeluC { h2v c[GDEG + 1]; h2v k2; };

// Packed-f16 polynomial GELU for a pair of f32 inputs.
__device__ __forceinline__ h2v gelu2(float lo, float hi, const GeluC& gc,
                                     h2v P3, h2v N3) {
    h2v x = __builtin_bit_cast(h2v, __builtin_amdgcn_cvt_pkrtz(lo, hi));
    h2v xc = __builtin_elementwise_min(__builtin_elementwise_max(x, N3), P3);
    h2v t = xc * xc;                              // u = xc^2 in [0,9]
    h2v s = t * gc.k2 - (_Float16)1.0f;           // s = u*(2/9) - 1 in [-1,1]
    h2v p = gc.c[GDEG];
    #pragma unroll
    for (int i = GDEG - 1; i >= 0; --i) p = p * s + gc.c[i];
    h2v w = xc * p;                               // ~ Phi(xc) - 0.5
    return x * w + x * (_Float16)0.5f;            // x*(0.5 + w)
}

// Pack two f32 C-tiles into a B-fragment (f16); g3 lanes: slot pair 6,7 =
// (1.0, 0) — the bias row k=30 and k=31 pad.
__device__ __forceinline__ h8 pack_b(f4 t0, f4 t1, bool g3) {
    union { unsigned u[4]; h8 v; } r;
    r.u[0] = __builtin_bit_cast(unsigned, __builtin_amdgcn_cvt_pkrtz(t0[0], t0[1]));
    r.u[1] = __builtin_bit_cast(unsigned, __builtin_amdgcn_cvt_pkrtz(t0[2], t0[3]));
    r.u[2] = __builtin_bit_cast(unsigned, __builtin_amdgcn_cvt_pkrtz(t1[0], t1[1]));
    r.u[3] = g3 ? 0x3C00u
                : __builtin_bit_cast(unsigned, __builtin_amdgcn_cvt_pkrtz(t1[2], t1[3]));
    return r.v;
}

// ---- prep: pack weights as A-fragments with κ(g,e); bias folded at k=30.
// ws layout (halves): tiles 0..7679 | gamma/beta f32 tab at 7680 (64 floats).
__global__ void prep(const float* __restrict__ w_emb, const float* __restrict__ b_emb,
                     const float* __restrict__ w_in,  const float* __restrict__ b_in,
                     const float* __restrict__ w_out, const float* __restrict__ b_out,
                     const float* __restrict__ w1,    const float* __restrict__ b1,
                     const float* __restrict__ w2,    const float* __restrict__ b2,
                     const float* __restrict__ gamma, const float* __restrict__ beta,
                     const float* __restrict__ w_o,   const float* __restrict__ b_o,
                     unsigned short* __restrict__ ws) {
    int t = blockIdx.x * 256 + threadIdx.x;
    // q pre-scale: 1/sqrt(10) * log2(e)  => softmax uses native exp2
    const float S = 0.31622776601683794f * 1.4426950408889634f;
    if (t < 960) {
        int tile = t >> 6, lane = t & 63;
        int g = lane >> 4;
        int mat = (tile == 14) ? 7 : (tile >> 1);
        int row = (tile & 1) * 16 + (lane & 15);   // output feature
        #pragma unroll
        for (int e = 0; e < 8; ++e) {
            int k = (e < 4) ? (4 * g + e) : (16 + 4 * g + (e - 4));
            float v = 0.f;
            switch (mat) {
              case 0: if (row<30) { if (k<5)  v = w_emb[row*5+k];        else if (k==30) v = b_emb[row]; } break;
              case 1: if (row<30) { if (k<30) v = w_in[row*30+k]*S;      else if (k==30) v = b_in[row]*S; } break;
              case 2: if (row<30) { if (k<30) v = w_in[(30+row)*30+k];   else if (k==30) v = b_in[30+row]; } break;
              case 3: if (row<30) { if (k<30) v = w_in[(60+row)*30+k];   else if (k==30) v = b_in[60+row]; } break;
              case 4: if (row<30) { if (k<30) v = w_out[row*30+k];       else if (k==30) v = b_out[row]; } break;
              case 5: if (row<30) { if (k<30) v = w1[row*30+k];          else if (k==30) v = b1[row]; } break;
              case 6: if (row<30) { if (k<30) v = w2[row*30+k];          else if (k==30) v = b2[row]; } break;
              case 7: if (row<3)  { if (k<30) v = w_o[row*30+k];         else if (k==30) v = b_o[row]; } break;
            }
            _Float16 hv = (_Float16)v;
            ws[tile * 512 + lane * 8 + e] = __builtin_bit_cast(unsigned short, hv);
        }
    } else if (t < 1024) {
        int f = t - 960;   // 0..63
        float* tab = (float*)(ws + 15 * 512);
        if (f < 32) tab[f] = (f < 30) ? gamma[f] : 0.f;
        else        tab[f] = (f - 32 < 30) ? beta[f - 32] : 0.f;
    }
}

#define RED2(x) { x += __shfl_xor(x, 16); x += __shfl_xor(x, 32); }

#define ITERS 8   // 16 elements per wave-iter

__global__ __launch_bounds__(256, 4) void model_kernel(
    const float* __restrict__ input,
    const unsigned short* __restrict__ ws,
    float* __restrict__ out, int B, GeluCU gcu)
{
    const int lane = threadIdx.x & 63;
    const int wv   = threadIdx.x >> 6;
    const int c    = lane & 15;     // batch column
    const int g    = lane >> 4;
    const bool g3  = (g == 3);
    const f4 Z = {0.f, 0.f, 0.f, 0.f};

    // ---- weight A-fragments (wave-wide, loop-invariant)
    const h8* wsf = (const h8*)ws;
    h8 Aemb0 = wsf[0*64+lane],  Aemb1 = wsf[1*64+lane];
    h8 Aq0   = wsf[2*64+lane],  Aq1   = wsf[3*64+lane];
    h8 Ak0   = wsf[4*64+lane],  Ak1   = wsf[5*64+lane];
    h8 Av0   = wsf[6*64+lane],  Av1   = wsf[7*64+lane];
    h8 Ao0   = wsf[8*64+lane],  Ao1   = wsf[9*64+lane];
    h8 A10   = wsf[10*64+lane], A11   = wsf[11*64+lane];
    h8 A20   = wsf[12*64+lane], A21   = wsf[13*64+lane];
    h8 Awo   = wsf[14*64+lane];

    const float* tab = (const float*)(ws + 15 * 512);
    f4 gaV0 = *(const f4*)&tab[4*g];
    f4 gaV1 = *(const f4*)&tab[16+4*g];
    f4 beV0 = *(const f4*)&tab[32+4*g];
    f4 beV1 = *(const f4*)&tab[48+4*g];

    // ---- gelu poly coefficients (kernel argument, uniform -> SGPRs)
    GeluC gc;
    #pragma unroll
    for (int i = 0; i <= GDEG; ++i) gc.c[i] = __builtin_bit_cast(h2v, gcu.c[i]);
    gc.k2 = __builtin_bit_cast(h2v, gcu.c[GDEG + 1]);
    const h2v P3 = {(_Float16)3.0f, (_Float16)3.0f};
    const h2v N3 = {(_Float16)-3.0f, (_Float16)-3.0f};

    // ---- head masks (loop-invariant)
    f4 m0v, m1v;
    #pragma unroll
    for (int r = 0; r < 4; ++r) {
        m0v[r] = (4 * g + r) < 10 ? 1.f : 0.f;
        m1v[r] = (16 + 4 * g + r) < 20 ? 1.f : 0.f;
    }

    for (int it = 0; it < ITERS; ++it) {
        const int eb = ((blockIdx.x * 4 + wv) * ITERS + it) * 16;
        int e = eb + c; if (e > B - 1) e = B - 1;
        const float* ip = input + (long)e * 10;

        // ---- embed B-frags (In^T): k=0..4 from input, k=30 bias row = 1.0
        f4u va = *(const f4u*)ip;        float v4 = ip[4];
        f4u vb = *(const f4u*)(ip + 5);  float v9 = ip[9];
        union { unsigned u[4]; h8 v; } bi0, bi1;
        unsigned pk01a = __builtin_bit_cast(unsigned, __builtin_amdgcn_cvt_pkrtz(va[0], va[1]));
        unsigned pk23a = __builtin_bit_cast(unsigned, __builtin_amdgcn_cvt_pkrtz(va[2], va[3]));
        unsigned pk4a  = __builtin_bit_cast(unsigned, __builtin_amdgcn_cvt_pkrtz(v4, 0.f));
        unsigned pk01b = __builtin_bit_cast(unsigned, __builtin_amdgcn_cvt_pkrtz(vb[0], vb[1]));
        unsigned pk23b = __builtin_bit_cast(unsigned, __builtin_amdgcn_cvt_pkrtz(vb[2], vb[3]));
        unsigned pk4b  = __builtin_bit_cast(unsigned, __builtin_amdgcn_cvt_pkrtz(v9, 0.f));
        bi0.u[0] = (g == 0) ? pk01a : ((g == 1) ? pk4a : 0u);
        bi0.u[1] = (g == 0) ? pk23a : 0u;
        bi0.u[2] = 0u;
        bi0.u[3] = g3 ? 0x3C00u : 0u;
        bi1.u[0] = (g == 0) ? pk01b : ((g == 1) ? pk4b : 0u);
        bi1.u[1] = (g == 0) ? pk23b : 0u;
        bi1.u[2] = 0u;
        bi1.u[3] = g3 ? 0x3C00u : 0u;

        // ---- embed pre-acts, then packed-f16 gelu
        f4 x0t0p = MF(Aemb0, bi0.v, Z);
        f4 x0t1p = MF(Aemb1, bi0.v, Z);
        f4 x1t0p = MF(Aemb0, bi1.v, Z);
        f4 x1t1p = MF(Aemb1, bi1.v, Z);

        h2v gx00 = gelu2(x0t0p[0], x0t0p[1], gc, P3, N3);
        h2v gx01 = gelu2(x0t0p[2], x0t0p[3], gc, P3, N3);
        h2v gx02 = gelu2(x0t1p[0], x0t1p[1], gc, P3, N3);
        h2v gx03 = gelu2(x0t1p[2], x0t1p[3], gc, P3, N3);
        h2v gx10 = gelu2(x1t0p[0], x1t0p[1], gc, P3, N3);
        h2v gx11 = gelu2(x1t0p[2], x1t0p[3], gc, P3, N3);
        h2v gx12 = gelu2(x1t1p[0], x1t1p[1], gc, P3, N3);
        h2v gx13 = gelu2(x1t1p[2], x1t1p[3], gc, P3, N3);

        union { unsigned u[4]; h8 v; } Bx0, Bx1;
        Bx0.u[0] = __builtin_bit_cast(unsigned, gx00);
        Bx0.u[1] = __builtin_bit_cast(unsigned, gx01);
        Bx0.u[2] = __builtin_bit_cast(unsigned, gx02);
        Bx0.u[3] = g3 ? 0x3C00u : __builtin_bit_cast(unsigned, gx03);
        Bx1.u[0] = __builtin_bit_cast(unsigned, gx10);
        Bx1.u[1] = __builtin_bit_cast(unsigned, gx11);
        Bx1.u[2] = __builtin_bit_cast(unsigned, gx12);
        Bx1.u[3] = g3 ? 0x3C00u : __builtin_bit_cast(unsigned, gx13);

        // x1 in f32 for the attention residual
        f4 x1t0, x1t1;
        x1t0[0]=(float)gx10[0]; x1t0[1]=(float)gx10[1]; x1t0[2]=(float)gx11[0]; x1t0[3]=(float)gx11[1];
        x1t1[0]=(float)gx12[0]; x1t1[1]=(float)gx12[1]; x1t1[2]=(float)gx13[0]; x1t1[3]=(float)gx13[1];

        // ---- QKV (q for token 1 only, pre-scaled by log2e/sqrt(10))
        f4 q0t  = MF(Aq0, Bx1.v, Z), q1t  = MF(Aq1, Bx1.v, Z);
        f4 k0t0 = MF(Ak0, Bx0.v, Z), k0t1 = MF(Ak1, Bx0.v, Z);
        f4 k1t0 = MF(Ak0, Bx1.v, Z), k1t1 = MF(Ak1, Bx1.v, Z);
        f4 v0t0 = MF(Av0, Bx0.v, Z), v0t1 = MF(Av1, Bx0.v, Z);
        f4 v1t0 = MF(Av0, Bx1.v, Z), v1t1 = MF(Av1, Bx1.v, Z);

        // ---- scores per head via mask-fma (no selects); scores in log2 units
        float tA0=0.f, tA1=0.f, tB0=0.f, tB1=0.f;
        float s0h0=0.f, s1h0=0.f, b0h1=0.f, b1h1=0.f;
        #pragma unroll
        for (int r = 0; r < 4; ++r) {
            float p00 = q0t[r]*k0t0[r], p10 = q0t[r]*k1t0[r];
            float p01 = q1t[r]*k0t1[r], p11 = q1t[r]*k1t1[r];
            tA0 += p00; s0h0 = fmaf(p00, m0v[r], s0h0);
            tA1 += p10; s1h0 = fmaf(p10, m0v[r], s1h0);
            tB0 += p01; b0h1 = fmaf(p01, m1v[r], b0h1);
            tB1 += p11; b1h1 = fmaf(p11, m1v[r], b1h1);
        }
        float s0h1 = tA0 - s0h0 + b0h1;
        float s0h2 = tB0 - b0h1;
        float s1h1 = tA1 - s1h0 + b1h1;
        float s1h2 = tB1 - b1h1;
        RED2(s0h0); RED2(s0h1); RED2(s0h2);
        RED2(s1h0); RED2(s1h1); RED2(s1h2);

        // scores bounded — no max-sub needed; native 2^x
        float e00 = exp2f(s0h0), e10 = exp2f(s1h0);
        float e01 = exp2f(s0h1), e11 = exp2f(s1h1);
        float e02 = exp2f(s0h2), e12 = exp2f(s1h2);
        float i0 = 1.f/(e00+e10), i1 = 1.f/(e01+e11), i2 = 1.f/(e02+e12);
        float a0h0 = e00*i0, a1h0 = e10*i0;
        float a0h1 = e01*i1, a1h1 = e11*i1;
        float a0h2 = e02*i2, a1h2 = e12*i2;
        float dA0 = a0h0-a0h1, dA1 = a1h0-a1h1;
        float dB0 = a0h1-a0h2, dB1 = a1h1-a1h2;

        // ---- ctx
        f4 ctx0, ctx1;
        #pragma unroll
        for (int r = 0; r < 4; ++r) {
            float A0 = fmaf(m0v[r], dA0, a0h1), A1 = fmaf(m0v[r], dA1, a1h1);
            ctx0[r] = fmaf(A1, v1t0[r], A0 * v0t0[r]);
            float B0 = fmaf(m1v[r], dB0, a0h2), B1 = fmaf(m1v[r], dB1, a1h2);
            ctx1[r] = fmaf(B1, v1t1[r], B0 * v0t1[r]);
        }

        // ---- attn out + residual(x1) via C-in
        h8 Bc = pack_b(ctx0, ctx1, g3);
        f4 t0 = MF(Ao0, Bc, x1t0);
        f4 t1 = MF(Ao1, Bc, x1t1);

        // ---- LN1
        float s = 0.f, ss = 0.f;
        #pragma unroll
        for (int r = 0; r < 4; ++r) {
            s  += t0[r] + t1[r];
            ss += t0[r]*t0[r] + t1[r]*t1[r];
        }
        RED2(s); RED2(ss);
        float mu = s * (1.f/30.f);
        float rs = rsqrtf(ss * (1.f/30.f) - mu*mu + EPS);
        f4 y0, y1;
        #pragma unroll
        for (int r = 0; r < 4; ++r) {
            y0[r] = fmaf((t0[r]-mu)*rs, gaV0[r], beV0[r]);
            y1[r] = fmaf((t1[r]-mu)*rs, gaV1[r], beV1[r]);
        }

        // ---- FFN1 pre-act + packed gelu
        h8 By = pack_b(y0, y1, g3);
        f4 hh0p = MF(A10, By, Z), hh1p = MF(A11, By, Z);
        h2v gh0 = gelu2(hh0p[0], hh0p[1], gc, P3, N3);
        h2v gh1 = gelu2(hh0p[2], hh0p[3], gc, P3, N3);
        h2v gh2 = gelu2(hh1p[0], hh1p[1], gc, P3, N3);
        h2v gh3 = gelu2(hh1p[2], hh1p[3], gc, P3, N3);
        union { unsigned u[4]; h8 v; } Bh;
        Bh.u[0] = __builtin_bit_cast(unsigned, gh0);
        Bh.u[1] = __builtin_bit_cast(unsigned, gh1);
        Bh.u[2] = __builtin_bit_cast(unsigned, gh2);
        Bh.u[3] = g3 ? 0x3C00u : __builtin_bit_cast(unsigned, gh3);

        // ---- FFN2 + residual(y) via C-in
        f4 u0 = MF(A20, Bh.v, y0), u1 = MF(A21, Bh.v, y1);

        // ---- LN2
        s = 0.f; ss = 0.f;
        #pragma unroll
        for (int r = 0; r < 4; ++r) {
            s  += u0[r] + u1[r];
            ss += u0[r]*u0[r] + u1[r]*u1[r];
        }
        RED2(s); RED2(ss);
        mu = s * (1.f/30.f);
        rs = rsqrtf(ss * (1.f/30.f) - mu*mu + EPS);
        f4 w0, w1;
        #pragma unroll
        for (int r = 0; r < 4; ++r) {
            w0[r] = fmaf((u0[r]-mu)*rs, gaV0[r], beV0[r]);
            w1[r] = fmaf((u1[r]-mu)*rs, gaV1[r], beV1[r]);
        }

        // ---- logits (rows 0..2 of tile0 => g==0 lanes' regs 0..2)
        h8 Bw = pack_b(w0, w1, g3);
        f4 lg = MF(Awo, Bw, Z);
        if (g == 0 && eb + c < B) {
            long base = (long)(eb + c) * 3;
            out[base]     = lg[0];
            out[base + 1] = lg[1];
            out[base + 2] = lg[2];
        }
    }
}

// Host float -> f16 bits (round-to-nearest-even); coefficients are normal-range.
static unsigned short f32_to_f16(float f) {
    unsigned x;
    __builtin_memcpy(&x, &f, 4);
    unsigned sign = (x >> 16) & 0x8000u;
    int exp = (int)((x >> 23) & 0xFFu) - 127 + 15;
    unsigned mant = x & 0x7FFFFFu;
    if (exp <= 0) {
        if (exp < -10) return (unsigned short)sign;
        mant |= 0x800000u;
        unsigned shift = (unsigned)(1 - exp) + 13;
        unsigned half = mant >> shift;
        unsigned rem = mant & ((1u << shift) - 1);
        unsigned halfway = 1u << (shift - 1);
        if (rem > halfway || (rem == halfway && (half & 1))) half++;
        return (unsigned short)(sign | half);
    }
    if (exp >= 31) return (unsigned short)(sign | 0x7C00u);
    unsigned half = sign | ((unsigned)exp << 10) | (mant >> 13);
    unsigned rem = mant & 0x1FFFu;
    if (rem > 0x1000u || (rem == 0x1000u && (half & 1))) half++;
    return (unsigned short)half;
}

extern "C" void kernel_launch(void* const* d_in, const int* in_sizes, int n_in,
                              void* d_out, int out_size, void* d_ws, size_t ws_size,
                              hipStream_t stream) {
    const float* input = (const float*)d_in[0];
    const float* w_emb = (const float*)d_in[1];
    const float* b_emb = (const float*)d_in[2];
    const float* w_in  = (const float*)d_in[3];
    const float* b_in  = (const float*)d_in[4];
    const float* w_out = (const float*)d_in[5];
    const float* b_out = (const float*)d_in[6];
    const float* w1    = (const float*)d_in[7];
    const float* b1    = (const float*)d_in[8];
    const float* w2    = (const float*)d_in[9];
    const float* b2    = (const float*)d_in[10];
    const float* gamma = (const float*)d_in[11];
    const float* beta  = (const float*)d_in[12];
    const float* w_o   = (const float*)d_in[13];
    const float* b_o   = (const float*)d_in[14];
    float* out = (float*)d_out;
    unsigned short* ws = (unsigned short*)d_ws;   // ~15.6 KB used

    const int B = in_sizes[0] / 10;

    // ---- host-side GELU poly fit (pure math constants, deterministic)
    GeluCU gcu;
    {
        const int NN = 64;
        double a[GDEG + 1];
        for (int j = 0; j <= GDEG; ++j) a[j] = 0.0;
        for (int k = 0; k < NN; ++k) {
            double th = M_PI * (k + 0.5) / NN;
            double sx = cos(th);
            double u  = 4.5 * (sx + 1.0);
            double z  = sqrt(u);
            double Phi = 0.5 * (1.0 + erf(z * 0.7071067811865476));
            double Gv  = (z > 1e-8) ? (Phi - 0.5) / z : 0.3989422804014327;
            for (int j = 0; j <= GDEG; ++j) a[j] += Gv * cos(j * th);
        }
        for (int j = 0; j <= GDEG; ++j) a[j] *= 2.0 / NN;
        a[0] *= 0.5;
        // Chebyshev -> monomial in s.
        double Tm[GDEG + 1][GDEG + 1];
        for (int i = 0; i <= GDEG; ++i)
            for (int j = 0; j <= GDEG; ++j) Tm[i][j] = 0.0;
        Tm[0][0] = 1.0; Tm[1][1] = 1.0;
        for (int k2 = 2; k2 <= GDEG; ++k2)
            for (int i = 0; i <= GDEG; ++i) {
                double v = -Tm[k2 - 2][i];
                if (i > 0) v += 2.0 * Tm[k2 - 1][i - 1];
                Tm[k2][i] = v;
            }
        for (int i = 0; i <= GDEG; ++i) {
            double m = 0.0;
            for (int j = 0; j <= GDEG; ++j) m += a[j] * Tm[j][i];
            unsigned short us = f32_to_f16((float)m);
            gcu.c[i] = (unsigned)us * 0x10001u;
        }
        unsigned short ku = f32_to_f16(2.0f / 9.0f);
        gcu.c[GDEG + 1] = (unsigned)ku * 0x10001u;
    }

    prep<<<4, 256, 0, stream>>>(w_emb, b_emb, w_in, b_in, w_out, b_out,
                                w1, b1, w2, b2, gamma, beta, w_o, b_o, ws);

    const int per_block = 4 * ITERS * 16;   // 512 elements
    const int blocks = (B + per_block - 1) / per_block;
    model_kernel<<<blocks, 256, 0, stream>>>(input, ws, out, B, gcu);
}

// Round 15
// 77.563 us; speedup vs baseline: 1.0392x; 1.0392x over previous
//
#include <hip/hip_runtime.h>
#include <math.h>

// Tiny 2-token transformer, E=30, H=3, D=10, B=1e6 — transposed-MFMA version.
// Y^T = W·X^T per layer with mfma_f32_16x16x32_f16; A = prep-packed weights
// (bias folded at k=30), B = activations^T built from C-regs by register
// packing (κ(g,e) = e<4 ? 4g+e : 16+4g+(e-4) shared by A and B).
// Round 15: EXACT restoration of round 11 (fastest verified-passing config:
// 78.2 µs, absmax 0.0078). Rounds 12/14 experiments (deg-6 GELU, exp2 fold +
// LN2 fold) produced small-absmax failures, two of them inexplicable by
// static analysis — per methodology, consolidate on the known-good kernel.
// Config: deg-9 packed-f16 GELU (host-fitted Chebyshev coeffs, by-value arg),
// __launch_bounds__(256,3) (occupancy 27->35%, the one proven lever),
// standard expf softmax, LN2 affine in-kernel.

typedef _Float16 h8 __attribute__((ext_vector_type(8)));
typedef _Float16 h2v __attribute__((ext_vector_type(2)));
typedef float f4 __attribute__((ext_vector_type(4)));
typedef f4 f4u __attribute__((aligned(4)));

#define EPS 1e-5f
#define GDEG 9

struct GeluCU { unsigned c[GDEG + 2]; };   // duplicated-half f16 pairs

__device__ __forceinline__ f4 MF(h8 a, h8 b, f4 c) {
    return __builtin_amdgcn_mfma_f32_16x16x32_f16(a, b, c, 0, 0, 0);
}

struct GeluC { h2v c[GDEG + 1]; h2v k2; };

// Packed-f16 polynomial GELU for a pair of f32 inputs.
__device__ __forceinline__ h2v gelu2(float lo, float hi, const GeluC& gc,
                                     h2v P3, h2v N3) {
    h2v x = __builtin_bit_cast(h2v, __builtin_amdgcn_cvt_pkrtz(lo, hi));
    h2v xc = __builtin_elementwise_min(__builtin_elementwise_max(x, N3), P3);
    h2v t = xc * xc;                              // u = xc^2 in [0,9]
    h2v s = t * gc.k2 - (_Float16)1.0f;           // s = u*(2/9) - 1 in [-1,1]
    h2v p = gc.c[GDEG];
    #pragma unroll
    for (int i = GDEG - 1; i >= 0; --i) p = p * s + gc.c[i];
    h2v w = xc * p;                               // ~ Phi(xc) - 0.5
    return x * w + x * (_Float16)0.5f;            // x*(0.5 + w)
}

// Pack two f32 C-tiles into a B-fragment (f16); g3 lanes: slot pair 6,7 =
// (1.0, 0) — the bias row k=30 and k=31 pad.
__device__ __forceinline__ h8 pack_b(f4 t0, f4 t1, bool g3) {
    union { unsigned u[4]; h8 v; } r;
    r.u[0] = __builtin_bit_cast(unsigned, __builtin_amdgcn_cvt_pkrtz(t0[0], t0[1]));
    r.u[1] = __builtin_bit_cast(unsigned, __builtin_amdgcn_cvt_pkrtz(t0[2], t0[3]));
    r.u[2] = __builtin_bit_cast(unsigned, __builtin_amdgcn_cvt_pkrtz(t1[0], t1[1]));
    r.u[3] = g3 ? 0x3C00u
                : __builtin_bit_cast(unsigned, __builtin_amdgcn_cvt_pkrtz(t1[2], t1[3]));
    return r.v;
}

// ---- prep: pack weights as A-fragments with κ(g,e); bias folded at k=30.
// ws layout (halves): tiles 0..7679 | gamma/beta f32 tab at 7680 (64 floats).
__global__ void prep(const float* __restrict__ w_emb, const float* __restrict__ b_emb,
                     const float* __restrict__ w_in,  const float* __restrict__ b_in,
                     const float* __restrict__ w_out, const float* __restrict__ b_out,
                     const float* __restrict__ w1,    const float* __restrict__ b1,
                     const float* __restrict__ w2,    const float* __restrict__ b2,
                     const float* __restrict__ gamma, const float* __restrict__ beta,
                     const float* __restrict__ w_o,   const float* __restrict__ b_o,
                     unsigned short* __restrict__ ws) {
    int t = blockIdx.x * 256 + threadIdx.x;
    const float S = 0.31622776601683794f;   // 1/sqrt(10)
    if (t < 960) {
        int tile = t >> 6, lane = t & 63;
        int g = lane >> 4;
        int mat = (tile == 14) ? 7 : (tile >> 1);
        int row = (tile & 1) * 16 + (lane & 15);   // output feature
        #pragma unroll
        for (int e = 0; e < 8; ++e) {
            int k = (e < 4) ? (4 * g + e) : (16 + 4 * g + (e - 4));
            float v = 0.f;
            switch (mat) {
              case 0: if (row<30) { if (k<5)  v = w_emb[row*5+k];        else if (k==30) v = b_emb[row]; } break;
              case 1: if (row<30) { if (k<30) v = w_in[row*30+k]*S;      else if (k==30) v = b_in[row]*S; } break;
              case 2: if (row<30) { if (k<30) v = w_in[(30+row)*30+k];   else if (k==30) v = b_in[30+row]; } break;
              case 3: if (row<30) { if (k<30) v = w_in[(60+row)*30+k];   else if (k==30) v = b_in[60+row]; } break;
              case 4: if (row<30) { if (k<30) v = w_out[row*30+k];       else if (k==30) v = b_out[row]; } break;
              case 5: if (row<30) { if (k<30) v = w1[row*30+k];          else if (k==30) v = b1[row]; } break;
              case 6: if (row<30) { if (k<30) v = w2[row*30+k];          else if (k==30) v = b2[row]; } break;
              case 7: if (row<3)  { if (k<30) v = w_o[row*30+k];         else if (k==30) v = b_o[row]; } break;
            }
            _Float16 hv = (_Float16)v;
            ws[tile * 512 + lane * 8 + e] = __builtin_bit_cast(unsigned short, hv);
        }
    } else if (t < 1024) {
        int f = t - 960;   // 0..63
        float* tab = (float*)(ws + 15 * 512);
        if (f < 32) tab[f] = (f < 30) ? gamma[f] : 0.f;
        else        tab[f] = (f - 32 < 30) ? beta[f - 32] : 0.f;
    }
}

#define RED2(x) { x += __shfl_xor(x, 16); x += __shfl_xor(x, 32); }

#define ITERS 8   // 16 elements per wave-iter

__global__ __launch_bounds__(256, 3) void model_kernel(
    const float* __restrict__ input,
    const unsigned short* __restrict__ ws,
    float* __restrict__ out, int B, GeluCU gcu)
{
    const int lane = threadIdx.x & 63;
    const int wv   = threadIdx.x >> 6;
    const int c    = lane & 15;     // batch column
    const int g    = lane >> 4;
    const bool g3  = (g == 3);
    const f4 Z = {0.f, 0.f, 0.f, 0.f};

    // ---- weight A-fragments (wave-wide, loop-invariant)
    const h8* wsf = (const h8*)ws;
    h8 Aemb0 = wsf[0*64+lane],  Aemb1 = wsf[1*64+lane];
    h8 Aq0   = wsf[2*64+lane],  Aq1   = wsf[3*64+lane];
    h8 Ak0   = wsf[4*64+lane],  Ak1   = wsf[5*64+lane];
    h8 Av0   = wsf[6*64+lane],  Av1   = wsf[7*64+lane];
    h8 Ao0   = wsf[8*64+lane],  Ao1   = wsf[9*64+lane];
    h8 A10   = wsf[10*64+lane], A11   = wsf[11*64+lane];
    h8 A20   = wsf[12*64+lane], A21   = wsf[13*64+lane];
    h8 Awo   = wsf[14*64+lane];

    const float* tab = (const float*)(ws + 15 * 512);
    f4 gaV0 = *(const f4*)&tab[4*g];
    f4 gaV1 = *(const f4*)&tab[16+4*g];
    f4 beV0 = *(const f4*)&tab[32+4*g];
    f4 beV1 = *(const f4*)&tab[48+4*g];

    // ---- gelu poly coefficients (kernel argument, uniform -> SGPRs)
    GeluC gc;
    #pragma unroll
    for (int i = 0; i <= GDEG; ++i) gc.c[i] = __builtin_bit_cast(h2v, gcu.c[i]);
    gc.k2 = __builtin_bit_cast(h2v, gcu.c[GDEG + 1]);
    const h2v P3 = {(_Float16)3.0f, (_Float16)3.0f};
    const h2v N3 = {(_Float16)-3.0f, (_Float16)-3.0f};

    // ---- head masks (loop-invariant)
    f4 m0v, m1v;
    #pragma unroll
    for (int r = 0; r < 4; ++r) {
        m0v[r] = (4 * g + r) < 10 ? 1.f : 0.f;
        m1v[r] = (16 + 4 * g + r) < 20 ? 1.f : 0.f;
    }

    for (int it = 0; it < ITERS; ++it) {
        const int eb = ((blockIdx.x * 4 + wv) * ITERS + it) * 16;
        int e = eb + c; if (e > B - 1) e = B - 1;
        const float* ip = input + (long)e * 10;

        // ---- embed B-frags (In^T): k=0..4 from input, k=30 bias row = 1.0
        f4u va = *(const f4u*)ip;        float v4 = ip[4];
        f4u vb = *(const f4u*)(ip + 5);  float v9 = ip[9];
        union { unsigned u[4]; h8 v; } bi0, bi1;
        unsigned pk01a = __builtin_bit_cast(unsigned, __builtin_amdgcn_cvt_pkrtz(va[0], va[1]));
        unsigned pk23a = __builtin_bit_cast(unsigned, __builtin_amdgcn_cvt_pkrtz(va[2], va[3]));
        unsigned pk4a  = __builtin_bit_cast(unsigned, __builtin_amdgcn_cvt_pkrtz(v4, 0.f));
        unsigned pk01b = __builtin_bit_cast(unsigned, __builtin_amdgcn_cvt_pkrtz(vb[0], vb[1]));
        unsigned pk23b = __builtin_bit_cast(unsigned, __builtin_amdgcn_cvt_pkrtz(vb[2], vb[3]));
        unsigned pk4b  = __builtin_bit_cast(unsigned, __builtin_amdgcn_cvt_pkrtz(v9, 0.f));
        bi0.u[0] = (g == 0) ? pk01a : ((g == 1) ? pk4a : 0u);
        bi0.u[1] = (g == 0) ? pk23a : 0u;
        bi0.u[2] = 0u;
        bi0.u[3] = g3 ? 0x3C00u : 0u;
        bi1.u[0] = (g == 0) ? pk01b : ((g == 1) ? pk4b : 0u);
        bi1.u[1] = (g == 0) ? pk23b : 0u;
        bi1.u[2] = 0u;
        bi1.u[3] = g3 ? 0x3C00u : 0u;

        // ---- embed pre-acts, then packed-f16 gelu
        f4 x0t0p = MF(Aemb0, bi0.v, Z);
        f4 x0t1p = MF(Aemb1, bi0.v, Z);
        f4 x1t0p = MF(Aemb0, bi1.v, Z);
        f4 x1t1p = MF(Aemb1, bi1.v, Z);

        h2v gx00 = gelu2(x0t0p[0], x0t0p[1], gc, P3, N3);
        h2v gx01 = gelu2(x0t0p[2], x0t0p[3], gc, P3, N3);
        h2v gx02 = gelu2(x0t1p[0], x0t1p[1], gc, P3, N3);
        h2v gx03 = gelu2(x0t1p[2], x0t1p[3], gc, P3, N3);
        h2v gx10 = gelu2(x1t0p[0], x1t0p[1], gc, P3, N3);
        h2v gx11 = gelu2(x1t0p[2], x1t0p[3], gc, P3, N3);
        h2v gx12 = gelu2(x1t1p[0], x1t1p[1], gc, P3, N3);
        h2v gx13 = gelu2(x1t1p[2], x1t1p[3], gc, P3, N3);

        union { unsigned u[4]; h8 v; } Bx0, Bx1;
        Bx0.u[0] = __builtin_bit_cast(unsigned, gx00);
        Bx0.u[1] = __builtin_bit_cast(unsigned, gx01);
        Bx0.u[2] = __builtin_bit_cast(unsigned, gx02);
        Bx0.u[3] = g3 ? 0x3C00u : __builtin_bit_cast(unsigned, gx03);
        Bx1.u[0] = __builtin_bit_cast(unsigned, gx10);
        Bx1.u[1] = __builtin_bit_cast(unsigned, gx11);
        Bx1.u[2] = __builtin_bit_cast(unsigned, gx12);
        Bx1.u[3] = g3 ? 0x3C00u : __builtin_bit_cast(unsigned, gx13);

        // x1 in f32 for the attention residual
        f4 x1t0, x1t1;
        x1t0[0]=(float)gx10[0]; x1t0[1]=(float)gx10[1]; x1t0[2]=(float)gx11[0]; x1t0[3]=(float)gx11[1];
        x1t1[0]=(float)gx12[0]; x1t1[1]=(float)gx12[1]; x1t1[2]=(float)gx13[0]; x1t1[3]=(float)gx13[1];

        // ---- QKV (q for token 1 only, pre-scaled by 1/sqrt(10))
        f4 q0t  = MF(Aq0, Bx1.v, Z), q1t  = MF(Aq1, Bx1.v, Z);
        f4 k0t0 = MF(Ak0, Bx0.v, Z), k0t1 = MF(Ak1, Bx0.v, Z);
        f4 k1t0 = MF(Ak0, Bx1.v, Z), k1t1 = MF(Ak1, Bx1.v, Z);
        f4 v0t0 = MF(Av0, Bx0.v, Z), v0t1 = MF(Av1, Bx0.v, Z);
        f4 v1t0 = MF(Av0, Bx1.v, Z), v1t1 = MF(Av1, Bx1.v, Z);

        // ---- scores per head via mask-fma (no selects)
        float tA0=0.f, tA1=0.f, tB0=0.f, tB1=0.f;
        float s0h0=0.f, s1h0=0.f, b0h1=0.f, b1h1=0.f;
        #pragma unroll
        for (int r = 0; r < 4; ++r) {
            float p00 = q0t[r]*k0t0[r], p10 = q0t[r]*k1t0[r];
            float p01 = q1t[r]*k0t1[r], p11 = q1t[r]*k1t1[r];
            tA0 += p00; s0h0 = fmaf(p00, m0v[r], s0h0);
            tA1 += p10; s1h0 = fmaf(p10, m0v[r], s1h0);
            tB0 += p01; b0h1 = fmaf(p01, m1v[r], b0h1);
            tB1 += p11; b1h1 = fmaf(p11, m1v[r], b1h1);
        }
        float s0h1 = tA0 - s0h0 + b0h1;
        float s0h2 = tB0 - b0h1;
        float s1h1 = tA1 - s1h0 + b1h1;
        float s1h2 = tB1 - b1h1;
        RED2(s0h0); RED2(s0h1); RED2(s0h2);
        RED2(s1h0); RED2(s1h1); RED2(s1h2);

        // scores bounded — no max-sub needed
        float e00 = __expf(s0h0), e10 = __expf(s1h0);
        float e01 = __expf(s0h1), e11 = __expf(s1h1);
        float e02 = __expf(s0h2), e12 = __expf(s1h2);
        float i0 = 1.f/(e00+e10), i1 = 1.f/(e01+e11), i2 = 1.f/(e02+e12);
        float a0h0 = e00*i0, a1h0 = e10*i0;
        float a0h1 = e01*i1, a1h1 = e11*i1;
        float a0h2 = e02*i2, a1h2 = e12*i2;
        float dA0 = a0h0-a0h1, dA1 = a1h0-a1h1;
        float dB0 = a0h1-a0h2, dB1 = a1h1-a1h2;

        // ---- ctx
        f4 ctx0, ctx1;
        #pragma unroll
        for (int r = 0; r < 4; ++r) {
            float A0 = fmaf(m0v[r], dA0, a0h1), A1 = fmaf(m0v[r], dA1, a1h1);
            ctx0[r] = fmaf(A1, v1t0[r], A0 * v0t0[r]);
            float B0 = fmaf(m1v[r], dB0, a0h2), B1 = fmaf(m1v[r], dB1, a1h2);
            ctx1[r] = fmaf(B1, v1t1[r], B0 * v0t1[r]);
        }

        // ---- attn out + residual(x1) via C-in
        h8 Bc = pack_b(ctx0, ctx1, g3);
        f4 t0 = MF(Ao0, Bc, x1t0);
        f4 t1 = MF(Ao1, Bc, x1t1);

        // ---- LN1
        float s = 0.f, ss = 0.f;
        #pragma unroll
        for (int r = 0; r < 4; ++r) {
            s  += t0[r] + t1[r];
            ss += t0[r]*t0[r] + t1[r]*t1[r];
        }
        RED2(s); RED2(ss);
        float mu = s * (1.f/30.f);
        float rs = rsqrtf(ss * (1.f/30.f) - mu*mu + EPS);
        f4 y0, y1;
        #pragma unroll
        for (int r = 0; r < 4; ++r) {
            y0[r] = fmaf((t0[r]-mu)*rs, gaV0[r], beV0[r]);
            y1[r] = fmaf((t1[r]-mu)*rs, gaV1[r], beV1[r]);
        }

        // ---- FFN1 pre-act + packed gelu
        h8 By = pack_b(y0, y1, g3);
        f4 hh0p = MF(A10, By, Z), hh1p = MF(A11, By, Z);
        h2v gh0 = gelu2(hh0p[0], hh0p[1], gc, P3, N3);
        h2v gh1 = gelu2(hh0p[2], hh0p[3], gc, P3, N3);
        h2v gh2 = gelu2(hh1p[0], hh1p[1], gc, P3, N3);
        h2v gh3 = gelu2(hh1p[2], hh1p[3], gc, P3, N3);
        union { unsigned u[4]; h8 v; } Bh;
        Bh.u[0] = __builtin_bit_cast(unsigned, gh0);
        Bh.u[1] = __builtin_bit_cast(unsigned, gh1);
        Bh.u[2] = __builtin_bit_cast(unsigned, gh2);
        Bh.u[3] = g3 ? 0x3C00u : __builtin_bit_cast(unsigned, gh3);

        // ---- FFN2 + residual(y) via C-in
        f4 u0 = MF(A20, Bh.v, y0), u1 = MF(A21, Bh.v, y1);

        // ---- LN2
        s = 0.f; ss = 0.f;
        #pragma unroll
        for (int r = 0; r < 4; ++r) {
            s  += u0[r] + u1[r];
            ss += u0[r]*u0[r] + u1[r]*u1[r];
        }
        RED2(s); RED2(ss);
        mu = s * (1.f/30.f);
        rs = rsqrtf(ss * (1.f/30.f) - mu*mu + EPS);
        f4 w0, w1;
        #pragma unroll
        for (int r = 0; r < 4; ++r) {
            w0[r] = fmaf((u0[r]-mu)*rs, gaV0[r], beV0[r]);
            w1[r] = fmaf((u1[r]-mu)*rs, gaV1[r], beV1[r]);
        }

        // ---- logits (rows 0..2 of tile0 => g==0 lanes' regs 0..2)
        h8 Bw = pack_b(w0, w1, g3);
        f4 lg = MF(Awo, Bw, Z);
        if (g == 0 && eb + c < B) {
            long base = (long)(eb + c) * 3;
            out[base]     = lg[0];
            out[base + 1] = lg[1];
            out[base + 2] = lg[2];
        }
    }
}

// Host float -> f16 bits (round-to-nearest-even); coefficients are normal-range.
static unsigned short f32_to_f16(float f) {
    unsigned x;
    __builtin_memcpy(&x, &f, 4);
    unsigned sign = (x >> 16) & 0x8000u;
    int exp = (int)((x >> 23) & 0xFFu) - 127 + 15;
    unsigned mant = x & 0x7FFFFFu;
    if (exp <= 0) {
        if (exp < -10) return (unsigned short)sign;
        mant |= 0x800000u;
        unsigned shift = (unsigned)(1 - exp) + 13;
        unsigned half = mant >> shift;
        unsigned rem = mant & ((1u << shift) - 1);
        unsigned halfway = 1u << (shift - 1);
        if (rem > halfway || (rem == halfway && (half & 1))) half++;
        return (unsigned short)(sign | half);
    }
    if (exp >= 31) return (unsigned short)(sign | 0x7C00u);
    unsigned half = sign | ((unsigned)exp << 10) | (mant >> 13);
    unsigned rem = mant & 0x1FFFu;
    if (rem > 0x1000u || (rem == 0x1000u && (half & 1))) half++;
    return (unsigned short)half;
}

extern "C" void kernel_launch(void* const* d_in, const int* in_sizes, int n_in,
                              void* d_out, int out_size, void* d_ws, size_t ws_size,
                              hipStream_t stream) {
    const float* input = (const float*)d_in[0];
    const float* w_emb = (const float*)d_in[1];
    const float* b_emb = (const float*)d_in[2];
    const float* w_in  = (const float*)d_in[3];
    const float* b_in  = (const float*)d_in[4];
    const float* w_out = (const float*)d_in[5];
    const float* b_out = (const float*)d_in[6];
    const float* w1    = (const float*)d_in[7];
    const float* b1    = (const float*)d_in[8];
    const float* w2    = (const float*)d_in[9];
    const float* b2    = (const float*)d_in[10];
    const float* gamma = (const float*)d_in[11];
    const float* beta  = (const float*)d_in[12];
    const float* w_o   = (const float*)d_in[13];
    const float* b_o   = (const float*)d_in[14];
    float* out = (float*)d_out;
    unsigned short* ws = (unsigned short*)d_ws;   // ~15.6 KB used

    const int B = in_sizes[0] / 10;

    // ---- host-side GELU poly fit (pure math constants, deterministic)
    GeluCU gcu;
    {
        const int NN = 64;
        double a[GDEG + 1];
        for (int j = 0; j <= GDEG; ++j) a[j] = 0.0;
        for (int k = 0; k < NN; ++k) {
            double th = M_PI * (k + 0.5) / NN;
            double sx = cos(th);
            double u  = 4.5 * (sx + 1.0);
            double z  = sqrt(u);
            double Phi = 0.5 * (1.0 + erf(z * 0.7071067811865476));
            double Gv  = (z > 1e-8) ? (Phi - 0.5) / z : 0.3989422804014327;
            for (int j = 0; j <= GDEG; ++j) a[j] += Gv * cos(j * th);
        }
        for (int j = 0; j <= GDEG; ++j) a[j] *= 2.0 / NN;
        a[0] *= 0.5;
        // Chebyshev -> monomial in s.
        double Tm[GDEG + 1][GDEG + 1];
        for (int i = 0; i <= GDEG; ++i)
            for (int j = 0; j <= GDEG; ++j) Tm[i][j] = 0.0;
        Tm[0][0] = 1.0; Tm[1][1] = 1.0;
        for (int k2 = 2; k2 <= GDEG; ++k2)
            for (int i = 0; i <= GDEG; ++i) {
                double v = -Tm[k2 - 2][i];
                if (i > 0) v += 2.0 * Tm[k2 - 1][i - 1];
                Tm[k2][i] = v;
            }
        for (int i = 0; i <= GDEG; ++i) {
            double m = 0.0;
            for (int j = 0; j <= GDEG; ++j) m += a[j] * Tm[j][i];
            unsigned short us = f32_to_f16((float)m);
            gcu.c[i] = (unsigned)us * 0x10001u;
        }
        unsigned short ku = f32_to_f16(2.0f / 9.0f);
        gcu.c[GDEG + 1] = (unsigned)ku * 0x10001u;
    }

    prep<<<4, 256, 0, stream>>>(w_emb, b_emb, w_in, b_in, w_out, b_out,
                                w1, b1, w2, b2, gamma, beta, w_o, b_o, ws);

    const int per_block = 4 * ITERS * 16;   // 512 elements
    const int blocks = (B + per_block - 1) / per_block;
    model_kernel<<<blocks, 256, 0, stream>>>(input, ws, out, B, gcu);
}

// Round 16
// 74.797 us; speedup vs baseline: 1.0776x; 1.0370x over previous
//
#include <hip/hip_runtime.h>
#include <math.h>

// Tiny 2-token transformer, E=30, H=3, D=10, B=1e6 — transposed-MFMA version.
// Y^T = W·X^T per layer with mfma_f32_16x16x32_f16; A = prep-packed weights
// (bias folded at k=30), B = activations^T built from C-regs by register
// packing (κ(g,e) = e<4 ? 4g+e : 16+4g+(e-4) shared by A and B).
// Round 16: round-15 body (verified 77.6 µs / absmax 0.0078) + depth-1
// software pipeline of the per-iteration INPUT LOAD only: iteration it+1's
// 40B load is issued right after iteration it's input values are consumed,
// hiding the ~300-900-cycle HBM/L2 latency under the ~4k-cycle body. Pure
// load scheduling — no arithmetic changes. Config: deg-9 packed-f16 GELU
// (host-fitted), __launch_bounds__(256,3), expf softmax, LN affines in-kernel.

typedef _Float16 h8 __attribute__((ext_vector_type(8)));
typedef _Float16 h2v __attribute__((ext_vector_type(2)));
typedef float f4 __attribute__((ext_vector_type(4)));
typedef f4 f4u __attribute__((aligned(4)));

#define EPS 1e-5f
#define GDEG 9

struct GeluCU { unsigned c[GDEG + 2]; };   // duplicated-half f16 pairs

__device__ __forceinline__ f4 MF(h8 a, h8 b, f4 c) {
    return __builtin_amdgcn_mfma_f32_16x16x32_f16(a, b, c, 0, 0, 0);
}

struct GeluC { h2v c[GDEG + 1]; h2v k2; };

// Packed-f16 polynomial GELU for a pair of f32 inputs.
__device__ __forceinline__ h2v gelu2(float lo, float hi, const GeluC& gc,
                                     h2v P3, h2v N3) {
    h2v x = __builtin_bit_cast(h2v, __builtin_amdgcn_cvt_pkrtz(lo, hi));
    h2v xc = __builtin_elementwise_min(__builtin_elementwise_max(x, N3), P3);
    h2v t = xc * xc;                              // u = xc^2 in [0,9]
    h2v s = t * gc.k2 - (_Float16)1.0f;           // s = u*(2/9) - 1 in [-1,1]
    h2v p = gc.c[GDEG];
    #pragma unroll
    for (int i = GDEG - 1; i >= 0; --i) p = p * s + gc.c[i];
    h2v w = xc * p;                               // ~ Phi(xc) - 0.5
    return x * w + x * (_Float16)0.5f;            // x*(0.5 + w)
}

// Pack two f32 C-tiles into a B-fragment (f16); g3 lanes: slot pair 6,7 =
// (1.0, 0) — the bias row k=30 and k=31 pad.
__device__ __forceinline__ h8 pack_b(f4 t0, f4 t1, bool g3) {
    union { unsigned u[4]; h8 v; } r;
    r.u[0] = __builtin_bit_cast(unsigned, __builtin_amdgcn_cvt_pkrtz(t0[0], t0[1]));
    r.u[1] = __builtin_bit_cast(unsigned, __builtin_amdgcn_cvt_pkrtz(t0[2], t0[3]));
    r.u[2] = __builtin_bit_cast(unsigned, __builtin_amdgcn_cvt_pkrtz(t1[0], t1[1]));
    r.u[3] = g3 ? 0x3C00u
                : __builtin_bit_cast(unsigned, __builtin_amdgcn_cvt_pkrtz(t1[2], t1[3]));
    return r.v;
}

// ---- prep: pack weights as A-fragments with κ(g,e); bias folded at k=30.
// ws layout (halves): tiles 0..7679 | gamma/beta f32 tab at 7680 (64 floats).
__global__ void prep(const float* __restrict__ w_emb, const float* __restrict__ b_emb,
                     const float* __restrict__ w_in,  const float* __restrict__ b_in,
                     const float* __restrict__ w_out, const float* __restrict__ b_out,
                     const float* __restrict__ w1,    const float* __restrict__ b1,
                     const float* __restrict__ w2,    const float* __restrict__ b2,
                     const float* __restrict__ gamma, const float* __restrict__ beta,
                     const float* __restrict__ w_o,   const float* __restrict__ b_o,
                     unsigned short* __restrict__ ws) {
    int t = blockIdx.x * 256 + threadIdx.x;
    const float S = 0.31622776601683794f;   // 1/sqrt(10)
    if (t < 960) {
        int tile = t >> 6, lane = t & 63;
        int g = lane >> 4;
        int mat = (tile == 14) ? 7 : (tile >> 1);
        int row = (tile & 1) * 16 + (lane & 15);   // output feature
        #pragma unroll
        for (int e = 0; e < 8; ++e) {
            int k = (e < 4) ? (4 * g + e) : (16 + 4 * g + (e - 4));
            float v = 0.f;
            switch (mat) {
              case 0: if (row<30) { if (k<5)  v = w_emb[row*5+k];        else if (k==30) v = b_emb[row]; } break;
              case 1: if (row<30) { if (k<30) v = w_in[row*30+k]*S;      else if (k==30) v = b_in[row]*S; } break;
              case 2: if (row<30) { if (k<30) v = w_in[(30+row)*30+k];   else if (k==30) v = b_in[30+row]; } break;
              case 3: if (row<30) { if (k<30) v = w_in[(60+row)*30+k];   else if (k==30) v = b_in[60+row]; } break;
              case 4: if (row<30) { if (k<30) v = w_out[row*30+k];       else if (k==30) v = b_out[row]; } break;
              case 5: if (row<30) { if (k<30) v = w1[row*30+k];          else if (k==30) v = b1[row]; } break;
              case 6: if (row<30) { if (k<30) v = w2[row*30+k];          else if (k==30) v = b2[row]; } break;
              case 7: if (row<3)  { if (k<30) v = w_o[row*30+k];         else if (k==30) v = b_o[row]; } break;
            }
            _Float16 hv = (_Float16)v;
            ws[tile * 512 + lane * 8 + e] = __builtin_bit_cast(unsigned short, hv);
        }
    } else if (t < 1024) {
        int f = t - 960;   // 0..63
        float* tab = (float*)(ws + 15 * 512);
        if (f < 32) tab[f] = (f < 30) ? gamma[f] : 0.f;
        else        tab[f] = (f - 32 < 30) ? beta[f - 32] : 0.f;
    }
}

#define RED2(x) { x += __shfl_xor(x, 16); x += __shfl_xor(x, 32); }

#define ITERS 8   // 16 elements per wave-iter

__global__ __launch_bounds__(256, 3) void model_kernel(
    const float* __restrict__ input,
    const unsigned short* __restrict__ ws,
    float* __restrict__ out, int B, GeluCU gcu)
{
    const int lane = threadIdx.x & 63;
    const int wv   = threadIdx.x >> 6;
    const int c    = lane & 15;     // batch column
    const int g    = lane >> 4;
    const bool g3  = (g == 3);
    const f4 Z = {0.f, 0.f, 0.f, 0.f};

    // ---- weight A-fragments (wave-wide, loop-invariant)
    const h8* wsf = (const h8*)ws;
    h8 Aemb0 = wsf[0*64+lane],  Aemb1 = wsf[1*64+lane];
    h8 Aq0   = wsf[2*64+lane],  Aq1   = wsf[3*64+lane];
    h8 Ak0   = wsf[4*64+lane],  Ak1   = wsf[5*64+lane];
    h8 Av0   = wsf[6*64+lane],  Av1   = wsf[7*64+lane];
    h8 Ao0   = wsf[8*64+lane],  Ao1   = wsf[9*64+lane];
    h8 A10   = wsf[10*64+lane], A11   = wsf[11*64+lane];
    h8 A20   = wsf[12*64+lane], A21   = wsf[13*64+lane];
    h8 Awo   = wsf[14*64+lane];

    const float* tab = (const float*)(ws + 15 * 512);
    f4 gaV0 = *(const f4*)&tab[4*g];
    f4 gaV1 = *(const f4*)&tab[16+4*g];
    f4 beV0 = *(const f4*)&tab[32+4*g];
    f4 beV1 = *(const f4*)&tab[48+4*g];

    // ---- gelu poly coefficients (kernel argument, uniform -> SGPRs)
    GeluC gc;
    #pragma unroll
    for (int i = 0; i <= GDEG; ++i) gc.c[i] = __builtin_bit_cast(h2v, gcu.c[i]);
    gc.k2 = __builtin_bit_cast(h2v, gcu.c[GDEG + 1]);
    const h2v P3 = {(_Float16)3.0f, (_Float16)3.0f};
    const h2v N3 = {(_Float16)-3.0f, (_Float16)-3.0f};

    // ---- head masks (loop-invariant)
    f4 m0v, m1v;
    #pragma unroll
    for (int r = 0; r < 4; ++r) {
        m0v[r] = (4 * g + r) < 10 ? 1.f : 0.f;
        m1v[r] = (16 + 4 * g + r) < 20 ? 1.f : 0.f;
    }

    // ---- depth-1 input prefetch: load iteration 0's input before the loop
    const int base_it = (blockIdx.x * 4 + wv) * ITERS;
    {
        int e0 = base_it * 16 + c; if (e0 > B - 1) e0 = B - 1;
        // nothing else — first load issued below
    }
    const float* ip0;
    {
        int e0 = base_it * 16 + c; if (e0 > B - 1) e0 = B - 1;
        ip0 = input + (long)e0 * 10;
    }
    f4u va = *(const f4u*)ip0;        float v4 = ip0[4];
    f4u vb = *(const f4u*)(ip0 + 5);  float v9 = ip0[9];

    for (int it = 0; it < ITERS; ++it) {
        const int eb = (base_it + it) * 16;

        // ---- consume current input: build embed B-frags (In^T)
        union { unsigned u[4]; h8 v; } bi0, bi1;
        unsigned pk01a = __builtin_bit_cast(unsigned, __builtin_amdgcn_cvt_pkrtz(va[0], va[1]));
        unsigned pk23a = __builtin_bit_cast(unsigned, __builtin_amdgcn_cvt_pkrtz(va[2], va[3]));
        unsigned pk4a  = __builtin_bit_cast(unsigned, __builtin_amdgcn_cvt_pkrtz(v4, 0.f));
        unsigned pk01b = __builtin_bit_cast(unsigned, __builtin_amdgcn_cvt_pkrtz(vb[0], vb[1]));
        unsigned pk23b = __builtin_bit_cast(unsigned, __builtin_amdgcn_cvt_pkrtz(vb[2], vb[3]));
        unsigned pk4b  = __builtin_bit_cast(unsigned, __builtin_amdgcn_cvt_pkrtz(v9, 0.f));
        bi0.u[0] = (g == 0) ? pk01a : ((g == 1) ? pk4a : 0u);
        bi0.u[1] = (g == 0) ? pk23a : 0u;
        bi0.u[2] = 0u;
        bi0.u[3] = g3 ? 0x3C00u : 0u;
        bi1.u[0] = (g == 0) ? pk01b : ((g == 1) ? pk4b : 0u);
        bi1.u[1] = (g == 0) ? pk23b : 0u;
        bi1.u[2] = 0u;
        bi1.u[3] = g3 ? 0x3C00u : 0u;

        // ---- issue next iteration's input load (clamped; last iter reloads self)
        {
            int itn = (it + 1 < ITERS) ? (it + 1) : it;
            int en = (base_it + itn) * 16 + c; if (en > B - 1) en = B - 1;
            const float* ipn = input + (long)en * 10;
            va = *(const f4u*)ipn;        v4 = ipn[4];
            vb = *(const f4u*)(ipn + 5);  v9 = ipn[9];
        }

        // ---- embed pre-acts, then packed-f16 gelu
        f4 x0t0p = MF(Aemb0, bi0.v, Z);
        f4 x0t1p = MF(Aemb1, bi0.v, Z);
        f4 x1t0p = MF(Aemb0, bi1.v, Z);
        f4 x1t1p = MF(Aemb1, bi1.v, Z);

        h2v gx00 = gelu2(x0t0p[0], x0t0p[1], gc, P3, N3);
        h2v gx01 = gelu2(x0t0p[2], x0t0p[3], gc, P3, N3);
        h2v gx02 = gelu2(x0t1p[0], x0t1p[1], gc, P3, N3);
        h2v gx03 = gelu2(x0t1p[2], x0t1p[3], gc, P3, N3);
        h2v gx10 = gelu2(x1t0p[0], x1t0p[1], gc, P3, N3);
        h2v gx11 = gelu2(x1t0p[2], x1t0p[3], gc, P3, N3);
        h2v gx12 = gelu2(x1t1p[0], x1t1p[1], gc, P3, N3);
        h2v gx13 = gelu2(x1t1p[2], x1t1p[3], gc, P3, N3);

        union { unsigned u[4]; h8 v; } Bx0, Bx1;
        Bx0.u[0] = __builtin_bit_cast(unsigned, gx00);
        Bx0.u[1] = __builtin_bit_cast(unsigned, gx01);
        Bx0.u[2] = __builtin_bit_cast(unsigned, gx02);
        Bx0.u[3] = g3 ? 0x3C00u : __builtin_bit_cast(unsigned, gx03);
        Bx1.u[0] = __builtin_bit_cast(unsigned, gx10);
        Bx1.u[1] = __builtin_bit_cast(unsigned, gx11);
        Bx1.u[2] = __builtin_bit_cast(unsigned, gx12);
        Bx1.u[3] = g3 ? 0x3C00u : __builtin_bit_cast(unsigned, gx13);

        // x1 in f32 for the attention residual
        f4 x1t0, x1t1;
        x1t0[0]=(float)gx10[0]; x1t0[1]=(float)gx10[1]; x1t0[2]=(float)gx11[0]; x1t0[3]=(float)gx11[1];
        x1t1[0]=(float)gx12[0]; x1t1[1]=(float)gx12[1]; x1t1[2]=(float)gx13[0]; x1t1[3]=(float)gx13[1];

        // ---- QKV (q for token 1 only, pre-scaled by 1/sqrt(10))
        f4 q0t  = MF(Aq0, Bx1.v, Z), q1t  = MF(Aq1, Bx1.v, Z);
        f4 k0t0 = MF(Ak0, Bx0.v, Z), k0t1 = MF(Ak1, Bx0.v, Z);
        f4 k1t0 = MF(Ak0, Bx1.v, Z), k1t1 = MF(Ak1, Bx1.v, Z);
        f4 v0t0 = MF(Av0, Bx0.v, Z), v0t1 = MF(Av1, Bx0.v, Z);
        f4 v1t0 = MF(Av0, Bx1.v, Z), v1t1 = MF(Av1, Bx1.v, Z);

        // ---- scores per head via mask-fma (no selects)
        float tA0=0.f, tA1=0.f, tB0=0.f, tB1=0.f;
        float s0h0=0.f, s1h0=0.f, b0h1=0.f, b1h1=0.f;
        #pragma unroll
        for (int r = 0; r < 4; ++r) {
            float p00 = q0t[r]*k0t0[r], p10 = q0t[r]*k1t0[r];
            float p01 = q1t[r]*k0t1[r], p11 = q1t[r]*k1t1[r];
            tA0 += p00; s0h0 = fmaf(p00, m0v[r], s0h0);
            tA1 += p10; s1h0 = fmaf(p10, m0v[r], s1h0);
            tB0 += p01; b0h1 = fmaf(p01, m1v[r], b0h1);
            tB1 += p11; b1h1 = fmaf(p11, m1v[r], b1h1);
        }
        float s0h1 = tA0 - s0h0 + b0h1;
        float s0h2 = tB0 - b0h1;
        float s1h1 = tA1 - s1h0 + b1h1;
        float s1h2 = tB1 - b1h1;
        RED2(s0h0); RED2(s0h1); RED2(s0h2);
        RED2(s1h0); RED2(s1h1); RED2(s1h2);

        // scores bounded — no max-sub needed
        float e00 = __expf(s0h0), e10 = __expf(s1h0);
        float e01 = __expf(s0h1), e11 = __expf(s1h1);
        float e02 = __expf(s0h2), e12 = __expf(s1h2);
        float i0 = 1.f/(e00+e10), i1 = 1.f/(e01+e11), i2 = 1.f/(e02+e12);
        float a0h0 = e00*i0, a1h0 = e10*i0;
        float a0h1 = e01*i1, a1h1 = e11*i1;
        float a0h2 = e02*i2, a1h2 = e12*i2;
        float dA0 = a0h0-a0h1, dA1 = a1h0-a1h1;
        float dB0 = a0h1-a0h2, dB1 = a1h1-a1h2;

        // ---- ctx
        f4 ctx0, ctx1;
        #pragma unroll
        for (int r = 0; r < 4; ++r) {
            float A0 = fmaf(m0v[r], dA0, a0h1), A1 = fmaf(m0v[r], dA1, a1h1);
            ctx0[r] = fmaf(A1, v1t0[r], A0 * v0t0[r]);
            float B0 = fmaf(m1v[r], dB0, a0h2), B1 = fmaf(m1v[r], dB1, a1h2);
            ctx1[r] = fmaf(B1, v1t1[r], B0 * v0t1[r]);
        }

        // ---- attn out + residual(x1) via C-in
        h8 Bc = pack_b(ctx0, ctx1, g3);
        f4 t0 = MF(Ao0, Bc, x1t0);
        f4 t1 = MF(Ao1, Bc, x1t1);

        // ---- LN1
        float s = 0.f, ss = 0.f;
        #pragma unroll
        for (int r = 0; r < 4; ++r) {
            s  += t0[r] + t1[r];
            ss += t0[r]*t0[r] + t1[r]*t1[r];
        }
        RED2(s); RED2(ss);
        float mu = s * (1.f/30.f);
        float rs = rsqrtf(ss * (1.f/30.f) - mu*mu + EPS);
        f4 y0, y1;
        #pragma unroll
        for (int r = 0; r < 4; ++r) {
            y0[r] = fmaf((t0[r]-mu)*rs, gaV0[r], beV0[r]);
            y1[r] = fmaf((t1[r]-mu)*rs, gaV1[r], beV1[r]);
        }

        // ---- FFN1 pre-act + packed gelu
        h8 By = pack_b(y0, y1, g3);
        f4 hh0p = MF(A10, By, Z), hh1p = MF(A11, By, Z);
        h2v gh0 = gelu2(hh0p[0], hh0p[1], gc, P3, N3);
        h2v gh1 = gelu2(hh0p[2], hh0p[3], gc, P3, N3);
        h2v gh2 = gelu2(hh1p[0], hh1p[1], gc, P3, N3);
        h2v gh3 = gelu2(hh1p[2], hh1p[3], gc, P3, N3);
        union { unsigned u[4]; h8 v; } Bh;
        Bh.u[0] = __builtin_bit_cast(unsigned, gh0);
        Bh.u[1] = __builtin_bit_cast(unsigned, gh1);
        Bh.u[2] = __builtin_bit_cast(unsigned, gh2);
        Bh.u[3] = g3 ? 0x3C00u : __builtin_bit_cast(unsigned, gh3);

        // ---- FFN2 + residual(y) via C-in
        f4 u0 = MF(A20, Bh.v, y0), u1 = MF(A21, Bh.v, y1);

        // ---- LN2
        s = 0.f; ss = 0.f;
        #pragma unroll
        for (int r = 0; r < 4; ++r) {
            s  += u0[r] + u1[r];
            ss += u0[r]*u0[r] + u1[r]*u1[r];
        }
        RED2(s); RED2(ss);
        mu = s * (1.f/30.f);
        rs = rsqrtf(ss * (1.f/30.f) - mu*mu + EPS);
        f4 w0, w1;
        #pragma unroll
        for (int r = 0; r < 4; ++r) {
            w0[r] = fmaf((u0[r]-mu)*rs, gaV0[r], beV0[r]);
            w1[r] = fmaf((u1[r]-mu)*rs, gaV1[r], beV1[r]);
        }

        // ---- logits (rows 0..2 of tile0 => g==0 lanes' regs 0..2)
        h8 Bw = pack_b(w0, w1, g3);
        f4 lg = MF(Awo, Bw, Z);
        if (g == 0 && eb + c < B) {
            long base = (long)(eb + c) * 3;
            out[base]     = lg[0];
            out[base + 1] = lg[1];
            out[base + 2] = lg[2];
        }
    }
}

// Host float -> f16 bits (round-to-nearest-even); coefficients are normal-range.
static unsigned short f32_to_f16(float f) {
    unsigned x;
    __builtin_memcpy(&x, &f, 4);
    unsigned sign = (x >> 16) & 0x8000u;
    int exp = (int)((x >> 23) & 0xFFu) - 127 + 15;
    unsigned mant = x & 0x7FFFFFu;
    if (exp <= 0) {
        if (exp < -10) return (unsigned short)sign;
        mant |= 0x800000u;
        unsigned shift = (unsigned)(1 - exp) + 13;
        unsigned half = mant >> shift;
        unsigned rem = mant & ((1u << shift) - 1);
        unsigned halfway = 1u << (shift - 1);
        if (rem > halfway || (rem == halfway && (half & 1))) half++;
        return (unsigned short)(sign | half);
    }
    if (exp >= 31) return (unsigned short)(sign | 0x7C00u);
    unsigned half = sign | ((unsigned)exp << 10) | (mant >> 13);
    unsigned rem = mant & 0x1FFFu;
    if (rem > 0x1000u || (rem == 0x1000u && (half & 1))) half++;
    return (unsigned short)half;
}

extern "C" void kernel_launch(void* const* d_in, const int* in_sizes, int n_in,
                              void* d_out, int out_size, void* d_ws, size_t ws_size,
                              hipStream_t stream) {
    const float* input = (const float*)d_in[0];
    const float* w_emb = (const float*)d_in[1];
    const float* b_emb = (const float*)d_in[2];
    const float* w_in  = (const float*)d_in[3];
    const float* b_in  = (const float*)d_in[4];
    const float* w_out = (const float*)d_in[5];
    const float* b_out = (const float*)d_in[6];
    const float* w1    = (const float*)d_in[7];
    const float* b1    = (const float*)d_in[8];
    const float* w2    = (const float*)d_in[9];
    const float* b2    = (const float*)d_in[10];
    const float* gamma = (const float*)d_in[11];
    const float* beta  = (const float*)d_in[12];
    const float* w_o   = (const float*)d_in[13];
    const float* b_o   = (const float*)d_in[14];
    float* out = (float*)d_out;
    unsigned short* ws = (unsigned short*)d_ws;   // ~15.6 KB used

    const int B = in_sizes[0] / 10;

    // ---- host-side GELU poly fit (pure math constants, deterministic)
    GeluCU gcu;
    {
        const int NN = 64;
        double a[GDEG + 1];
        for (int j = 0; j <= GDEG; ++j) a[j] = 0.0;
        for (int k = 0; k < NN; ++k) {
            double th = M_PI * (k + 0.5) / NN;
            double sx = cos(th);
            double u  = 4.5 * (sx + 1.0);
            double z  = sqrt(u);
            double Phi = 0.5 * (1.0 + erf(z * 0.7071067811865476));
            double Gv  = (z > 1e-8) ? (Phi - 0.5) / z : 0.3989422804014327;
            for (int j = 0; j <= GDEG; ++j) a[j] += Gv * cos(j * th);
        }
        for (int j = 0; j <= GDEG; ++j) a[j] *= 2.0 / NN;
        a[0] *= 0.5;
        // Chebyshev -> monomial in s.
        double Tm[GDEG + 1][GDEG + 1];
        for (int i = 0; i <= GDEG; ++i)
            for (int j = 0; j <= GDEG; ++j) Tm[i][j] = 0.0;
        Tm[0][0] = 1.0; Tm[1][1] = 1.0;
        for (int k2 = 2; k2 <= GDEG; ++k2)
            for (int i = 0; i <= GDEG; ++i) {
                double v = -Tm[k2 - 2][i];
                if (i > 0) v += 2.0 * Tm[k2 - 1][i - 1];
                Tm[k2][i] = v;
            }
        for (int i = 0; i <= GDEG; ++i) {
            double m = 0.0;
            for (int j = 0; j <= GDEG; ++j) m += a[j] * Tm[j][i];
            unsigned short us = f32_to_f16((float)m);
            gcu.c[i] = (unsigned)us * 0x10001u;
        }
        unsigned short ku = f32_to_f16(2.0f / 9.0f);
        gcu.c[GDEG + 1] = (unsigned)ku * 0x10001u;
    }

    prep<<<4, 256, 0, stream>>>(w_emb, b_emb, w_in, b_in, w_out, b_out,
                                w1, b1, w2, b2, gamma, beta, w_o, b_o, ws);

    const int per_block = 4 * ITERS * 16;   // 512 elements
    const int blocks = (B + per_block - 1) / per_block;
    model_kernel<<<blocks, 256, 0, stream>>>(input, ws, out, B, gcu);
}